// Round 5
// baseline (547.744 us; speedup 1.0000x reference)
//
#include <hip/hip_runtime.h>
#include <math.h>

#define L2C   65536
#define NC    (2 * L2C)
#define FINC  8
#define FOUTC 8
#define KC    13
#define BLOCK 256
#define EPB   4
#define EWORDS (FOUTC * FINC * KC)    // 832 mask elements per edge
#define TILE_WBYTES (EPB * EWORDS * 4) // 13312 B: one tile of int32 masks
#define TILE_BBYTES (EPB * EWORDS)     // 3328 B: one tile of bool masks
#define GRID   2048                   // 8 blocks/CU resident (persistent-style)
#define TILES_PER_BLOCK 16            // 32768 tiles total, 16 contiguous per block

constexpr double E_D = 2.71828182845904523536;
constexpr float SCALE_F = (float)((2.0 + 2.0 * E_D) / (E_D - 1.0));

// d_ws: xt = x transposed to (N, FIN), 4 MiB at offset 0.

// x (FIN, N) -> xt (N, FIN): a gathered column becomes one 32 B segment.
__global__ __launch_bounds__(256)
void transpose_x_kernel(const float* __restrict__ x, float* __restrict__ xt) {
    int n = blockIdx.x * 256 + threadIdx.x;
    float v[FINC];
#pragma unroll
    for (int i = 0; i < FINC; ++i) v[i] = x[(size_t)i * NC + n];
    float4* dst = reinterpret_cast<float4*>(xt + ((size_t)n << 3));
    dst[0] = make_float4(v[0], v[1], v[2], v[3]);
    dst[1] = make_float4(v[4], v[5], v[6], v[7]);
}

// R12 = R11 with the addressing bug fixed: R11 computed mask tile bases as
// lb*(EWORDS*4) — one EDGE stride — instead of lb*TILE_WBYTES (one TILE = 4
// edges). Wrong masks from tile 1 onward -> absmax 3.3. Structure unchanged:
//
// R1/R2/R3 all pinned at ~2.9-3.3 TB/s device-read regardless of mask path
// (ballot chain / pure-stream pack / LDS staging) — the common factor was
// one-shot blocks: lifetime = issue -> HBM stall -> barrier -> short compute
// -> die, 32768 launches. This version keeps a continuous load pipeline:
// 2048 persistent-style blocks (8/CU, 32 waves/CU), each runs 16 contiguous
// tiles with issue-early/write-late staging (T14):
//   issue tile t+1 global_load_dwordx4 -> regs   (latency hides under...)
//   compute tile t from LDS (cols -> xt gather -> mask-select FMA)
//   barrier; store tile t output (LDS-repacked, 8x dwordx4); ds_write regs
//   barrier
// Mask reads per lane stay lane-local in LDS (layout [e][o][i][k], lane's
// 13 words contiguous at lane*13; 13*lane mod 32 bijective -> 2-way -> free).
__global__ __launch_bounds__(BLOCK, 8)
void edge_conv_kernel(const float* __restrict__ xt,
                      const float* __restrict__ Wh, const float* __restrict__ Wv,
                      const float* __restrict__ bh, const float* __restrict__ bv,
                      const unsigned char* __restrict__ mh,
                      const unsigned char* __restrict__ mv,
                      const int* __restrict__ kh, const int* __restrict__ kv,
                      float* __restrict__ out)
{
    __shared__ float        Wsh[EWORDS];          // 3328 B, flat [o][i][k]
    __shared__ unsigned int msh[EPB * EWORDS];    // 13312 B (one tile of masks)
    __shared__ float        osh[FOUTC][EPB];      // output repack, 128 B

    const int tid  = threadIdx.x;
    const int lane = tid & 63;
    const int wave = tid >> 6;
    const int o    = lane >> 3;
    const int i    = lane & 7;

    const int  b   = blockIdx.x;
    const bool hor = (b < GRID / 2);
    const int  lb  = (hor ? b : b - GRID / 2) * TILES_PER_BLOCK; // local tile base

    const float*         W    = hor ? Wh  : Wv;
    const float*         bias = hor ? bh  : bv;
    const unsigned char* mask = hor ? mh  : mv;
    const int*           ker  = hor ? kh  : kv;

    // Mask-encoding probe (proven): int32/float32 0/1 masks have byte
    // offset%4==1 always zero; 1-byte bools are random. Grid-uniform.
    const unsigned char probe = mh[(size_t)(lane * 4 + 1)];
    const bool words = (__ballot(probe != 0) == 0ull);

    // Weights + per-lane bias once per block.
    if (tid < EWORDS / 4)
        reinterpret_cast<float4*>(Wsh)[tid] = reinterpret_cast<const float4*>(W)[tid];
    const float biaso = bias[o];

    uint4 r0, r1, r2, r3;

    // Prologue: stage tile lb. (Tile t starts at byte t*TILE_WBYTES / t*TILE_BBYTES.)
    if (words) {
        const uint4* g4 = reinterpret_cast<const uint4*>(mask + (size_t)lb * TILE_WBYTES);
        r0 = g4[tid]; r1 = g4[tid + 256]; r2 = g4[tid + 512];
        if (tid < 64) r3 = g4[tid + 768];
        uint4* m4 = reinterpret_cast<uint4*>(msh);
        m4[tid] = r0; m4[tid + 256] = r1; m4[tid + 512] = r2;
        if (tid < 64) m4[tid + 768] = r3;
    } else {
        const uint4* g4 = reinterpret_cast<const uint4*>(mask + (size_t)lb * TILE_BBYTES);
        if (tid < 208) {
            r0 = g4[tid];
            reinterpret_cast<uint4*>(msh)[tid] = r0;
        }
    }
    __syncthreads();

    for (int it = 0; it < TILES_PER_BLOCK; ++it) {
        const int bblk = lb + it;

        // 1) issue prefetch of tile it+1 into regs (completes under compute).
        if (it + 1 < TILES_PER_BLOCK) {
            if (words) {
                const uint4* g4 = reinterpret_cast<const uint4*>(
                    mask + (size_t)(bblk + 1) * TILE_WBYTES);
                r0 = g4[tid]; r1 = g4[tid + 256]; r2 = g4[tid + 512];
                if (tid < 64) r3 = g4[tid + 768];
            } else {
                const uint4* g4 = reinterpret_cast<const uint4*>(
                    mask + (size_t)(bblk + 1) * TILE_BBYTES);
                if (tid < 208) r0 = g4[tid];
            }
        }

        // 2) compute current tile. cols head the longest dep chain.
        const int be = bblk * EPB + wave;
        int cols[KC];
#pragma unroll
        for (int k = 0; k < KC; ++k) cols[k] = ker[(size_t)be * KC + k];

        float acc0 = 0.0f, acc1 = 0.0f;
        if (words) {
            const unsigned int* mrow = msh + wave * EWORDS + lane * KC;
#pragma unroll
            for (int k = 0; k < KC; ++k) {
                const float xv = xt[((size_t)cols[k] << 3) + i]; // 32 B seg / wave / k
                const float wk = Wsh[lane * KC + k];             // 2-way alias: free
                const float wm = mrow[k] ? wk : 0.0f;
                if (k & 1) acc1 = fmaf(wm, xv, acc1);
                else       acc0 = fmaf(wm, xv, acc0);
            }
        } else {
            const unsigned char* mrow = reinterpret_cast<const unsigned char*>(msh)
                                        + wave * EWORDS + lane * KC;
#pragma unroll
            for (int k = 0; k < KC; ++k) {
                const float xv = xt[((size_t)cols[k] << 3) + i];
                const float wk = Wsh[lane * KC + k];
                const float wm = mrow[k] ? wk : 0.0f;
                if (k & 1) acc1 = fmaf(wm, xv, acc1);
                else       acc0 = fmaf(wm, xv, acc0);
            }
        }
        float acc = acc0 + acc1;
        acc += __shfl_xor(acc, 1);
        acc += __shfl_xor(acc, 2);
        acc += __shfl_xor(acc, 4);
        if (i == 0) {
            const float z   = acc + biaso;
            const float sig = 1.0f / (1.0f + __expf(-z));
            osh[o][wave] = (sig - 0.5f) * SCALE_F;
        }

        __syncthreads();   // msh fully consumed; osh complete

        // 3) store current tile's output: 8 rows x 4 contiguous cols, dwordx4.
        if (tid < FOUTC) {
            const int colbase = (hor ? 0 : L2C) + bblk * EPB;
            *reinterpret_cast<float4*>(out + (size_t)tid * NC + colbase) =
                *reinterpret_cast<const float4*>(&osh[tid][0]);
        }

        // 4) land prefetched regs into msh for the next iteration.
        if (it + 1 < TILES_PER_BLOCK) {
            if (words) {
                uint4* m4 = reinterpret_cast<uint4*>(msh);
                m4[tid] = r0; m4[tid + 256] = r1; m4[tid + 512] = r2;
                if (tid < 64) m4[tid + 768] = r3;
            } else {
                if (tid < 208) reinterpret_cast<uint4*>(msh)[tid] = r0;
            }
        }
        __syncthreads();
    }
}

extern "C" void kernel_launch(void* const* d_in, const int* in_sizes, int n_in,
                              void* d_out, int out_size, void* d_ws, size_t ws_size,
                              hipStream_t stream) {
    const float*         x   = (const float*)d_in[0];
    const float*         Wh  = (const float*)d_in[1];
    const float*         Wv  = (const float*)d_in[2];
    const float*         bh  = (const float*)d_in[3];
    const float*         bv  = (const float*)d_in[4];
    const unsigned char* mh  = (const unsigned char*)d_in[5];
    const unsigned char* mv  = (const unsigned char*)d_in[6];
    const int*           kh  = (const int*)d_in[7];
    const int*           kv  = (const int*)d_in[8];
    float* out = (float*)d_out;
    float* xt  = (float*)d_ws;

    transpose_x_kernel<<<NC / 256, 256, 0, stream>>>(x, xt);
    edge_conv_kernel<<<GRID, BLOCK, 0, stream>>>(
        xt, Wh, Wv, bh, bv, mh, mv, kh, kv, out);
}

// Round 6
// 455.183 us; speedup vs baseline: 1.2033x; 1.2033x over previous
//
#include <hip/hip_runtime.h>
#include <math.h>

#define L2C   65536
#define NC    (2 * L2C)
#define FINC  8
#define FOUTC 8
#define KC    13
#define BLOCK 256
#define EPB   4
#define EWORDS (FOUTC * FINC * KC)     // 832 mask elements per edge
#define TILE_WORDS (EPB * EWORDS)      // 3328 dwords per tile (int32-mask mode)
#define TILE_WBYTES (TILE_WORDS * 4)   // 13312 B
#define TILE_BBYTES (EPB * EWORDS)     // 3328 B (bool-mask mode)
#define GRID  1536                     // 6 blocks/CU (LDS-limited) -> ALL resident
#define GRIDH (GRID / 2)               // 768 blocks per branch
#define TPBR  (L2C / EPB)              // 16384 tiles per branch

constexpr double E_D = 2.71828182845904523536;
constexpr float SCALE_F = (float)((2.0 + 2.0 * E_D) / (E_D - 1.0));

typedef unsigned int u32;
typedef __attribute__((address_space(1))) const u32 gu32;
typedef __attribute__((address_space(3))) u32 lu32;

// Direct global->LDS DMA, 16 B per lane. LDS dest = wave-uniform base +
// lane*16 (hardware-defined); our staging layout is exactly linear.
__device__ __forceinline__ void gll16(const void* g, u32* l) {
    __builtin_amdgcn_global_load_lds((gu32*)g, (lu32*)l, 16, 0, 0);
}

// d_ws: xt = x transposed to (N, FIN), 4 MiB at offset 0.
__global__ __launch_bounds__(256)
void transpose_x_kernel(const float* __restrict__ x, float* __restrict__ xt) {
    int n = blockIdx.x * 256 + threadIdx.x;
    float v[FINC];
#pragma unroll
    for (int i = 0; i < FINC; ++i) v[i] = x[(size_t)i * NC + n];
    float4* dst = reinterpret_cast<float4*>(xt + ((size_t)n << 3));
    dst[0] = make_float4(v[0], v[1], v[2], v[3]);
    dst[1] = make_float4(v[4], v[5], v[6], v[7]);
}

// R13: R5 proved the persistent pipeline streams (3.54 TB/s, best yet) but
// __launch_bounds__(256,8)'s 64-VGPR cap spilled the 16 prefetch registers
// (WRITE_SIZE 8->313 MB, FETCH +212 MB = scratch round-trips, VALU 10.7%).
// Fix: no staging registers at all — global_load_lds (width 16) into a
// double-buffered LDS tile. Per iteration: issue next tile's glls -> compute
// current tile from LDS -> one __syncthreads() (its vmcnt(0) drains glls
// that had the whole compute phase to land). Grid-stride tile loop: the
// resident 1536 blocks sweep consecutive tiles (contiguous footprint).
// Mask reads stay lane-local (layout [e][o][i][k]: lane's 13 words at
// lane*13; 13*lane mod 32 bijective -> 2 lanes/bank -> free, m136).
__global__ __launch_bounds__(BLOCK, 6)
void edge_conv_kernel(const float* __restrict__ xt,
                      const float* __restrict__ Wh, const float* __restrict__ Wv,
                      const float* __restrict__ bh, const float* __restrict__ bv,
                      const unsigned char* __restrict__ mh,
                      const unsigned char* __restrict__ mv,
                      const int* __restrict__ kh, const int* __restrict__ kv,
                      float* __restrict__ out)
{
    __shared__ __align__(16) u32 msh[2][TILE_WORDS];   // 2 x 13312 B

    const int tid  = threadIdx.x;
    const int lane = tid & 63;
    const int wave = tid >> 6;
    const int o    = lane >> 3;
    const int i    = lane & 7;

    const int  b     = blockIdx.x;
    const bool hor   = (b < GRIDH);
    const int  bb    = hor ? b : b - GRIDH;
    const int  cbase = hor ? 0 : L2C;

    const float*         W    = hor ? Wh : Wv;
    const float*         bias = hor ? bh : bv;
    const unsigned char* mask = hor ? mh : mv;
    const int*           ker  = hor ? kh : kv;

    // Mask-encoding probe (proven): int32/float32 0/1 masks have byte
    // offset%4==1 always zero; 1-byte bools are random. Grid-uniform.
    const unsigned char probe = mh[(size_t)(lane * 4 + 1)];
    const bool words = (__ballot(probe != 0) == 0ull);

    // Per-lane weight row + bias, loaded once (L2/L3-cached, reused 21x).
    float wreg[KC];
#pragma unroll
    for (int k = 0; k < KC; ++k) wreg[k] = W[lane * KC + k];
    const float biaso = bias[o];

    // Stage one tile into msh[buf] via global_load_lds.
    // words: 832 uint4 = 13 chunks of 64; wave handles c = wave, wave+4,
    //        wave+8; wave 0 also c=12. LDS base uniform per instr; HW adds
    //        lane*16 -> linear, matching the flat tile layout.
    // bytes: 208 uint4 = chunks 0..2 (waves 0-2) + 16 uint4 (wave 3, lane<16).
    auto stage = [&](int buf, int t) {
        if (words) {
            const char* g = (const char*)mask + (size_t)t * TILE_WBYTES;
#pragma unroll
            for (int j = 0; j < 3; ++j) {
                const int c = wave + 4 * j;
                gll16(g + (size_t)(c * 64 + lane) * 16, &msh[buf][c * 256]);
            }
            if (wave == 0)
                gll16(g + (size_t)(12 * 64 + lane) * 16, &msh[buf][12 * 256]);
        } else {
            const char* g = (const char*)mask + (size_t)t * TILE_BBYTES;
            if (wave < 3)
                gll16(g + (size_t)(wave * 64 + lane) * 16, &msh[buf][wave * 256]);
            else if (lane < 16)
                gll16(g + (size_t)(3 * 64 + lane) * 16, &msh[buf][3 * 256]);
        }
    };

    int t = bb;
    stage(0, t);
    __syncthreads();                       // drains prologue glls (vmcnt 0)

    int buf = 0;
    for (; t < TPBR; t += GRIDH, buf ^= 1) {
        const int tn = t + GRIDH;
        if (tn < TPBR) stage(buf ^ 1, tn); // issue-early: lands under compute

        const int be  = t * EPB + wave;
        const int bes = __builtin_amdgcn_readfirstlane(be);  // force SMEM ker loads

        int cols[KC];
#pragma unroll
        for (int k = 0; k < KC; ++k) cols[k] = ker[(size_t)bes * KC + k];

        float acc0 = 0.0f, acc1 = 0.0f;
        if (words) {
            const u32* mrow = &msh[buf][wave * EWORDS + lane * KC];
#pragma unroll
            for (int k = 0; k < KC; ++k) {
                const float xv = xt[((size_t)cols[k] << 3) + i]; // 32 B seg / wave / k
                const float wm = mrow[k] ? wreg[k] : 0.0f;
                if (k & 1) acc1 = fmaf(wm, xv, acc1);
                else       acc0 = fmaf(wm, xv, acc0);
            }
        } else {
            const unsigned char* mrow = (const unsigned char*)&msh[buf][0]
                                        + wave * EWORDS + lane * KC;
#pragma unroll
            for (int k = 0; k < KC; ++k) {
                const float xv = xt[((size_t)cols[k] << 3) + i];
                const float wm = mrow[k] ? wreg[k] : 0.0f;
                if (k & 1) acc1 = fmaf(wm, xv, acc1);
                else       acc0 = fmaf(wm, xv, acc0);
            }
        }
        float acc = acc0 + acc1;
        acc += __shfl_xor(acc, 1);
        acc += __shfl_xor(acc, 2);
        acc += __shfl_xor(acc, 4);
        const float z = acc + biaso;

        __syncthreads();   // all waves done reading msh[buf]; glls for tn drained

        if (i == 0) {      // store after the barrier: keeps it out of the drain
            const float sig = 1.0f / (1.0f + __expf(-z));
            out[(size_t)o * NC + (cbase + be)] = (sig - 0.5f) * SCALE_F;
        }
    }
}

extern "C" void kernel_launch(void* const* d_in, const int* in_sizes, int n_in,
                              void* d_out, int out_size, void* d_ws, size_t ws_size,
                              hipStream_t stream) {
    const float*         x   = (const float*)d_in[0];
    const float*         Wh  = (const float*)d_in[1];
    const float*         Wv  = (const float*)d_in[2];
    const float*         bh  = (const float*)d_in[3];
    const float*         bv  = (const float*)d_in[4];
    const unsigned char* mh  = (const unsigned char*)d_in[5];
    const unsigned char* mv  = (const unsigned char*)d_in[6];
    const int*           kh  = (const int*)d_in[7];
    const int*           kv  = (const int*)d_in[8];
    float* out = (float*)d_out;
    float* xt  = (float*)d_ws;

    transpose_x_kernel<<<NC / 256, 256, 0, stream>>>(x, xt);
    edge_conv_kernel<<<GRID, BLOCK, 0, stream>>>(
        xt, Wh, Wv, bh, bv, mh, mv, kh, kv, out);
}

// Round 7
// 440.144 us; speedup vs baseline: 1.2445x; 1.0342x over previous
//
#include <hip/hip_runtime.h>
#include <math.h>

#define L2C   65536
#define NC    (2 * L2C)
#define FINC  8
#define FOUTC 8
#define KC    13
#define BLOCK 256
#define EPB   4
#define EWORDS (FOUTC * FINC * KC)     // 832 mask elements per edge
#define TILE_WORDS (EPB * EWORDS)      // 3328 dwords per tile (int32-mask mode)
#define TILE_WBYTES (TILE_WORDS * 4)   // 13312 B
#define TILE_BBYTES (EPB * EWORDS)     // 3328 B (bool-mask mode)
#define GRID  1536                     // 6 blocks/CU (LDS-limited) -> ALL resident
#define GRIDH (GRID / 2)               // 768 blocks per branch
#define TPBR  (L2C / EPB)              // 16384 tiles per branch

constexpr double E_D = 2.71828182845904523536;
constexpr float SCALE_F = (float)((2.0 + 2.0 * E_D) / (E_D - 1.0));

typedef unsigned int u32;
typedef __attribute__((address_space(1))) const u32 gu32;
typedef __attribute__((address_space(3))) u32 lu32;

// Direct global->LDS DMA, 16 B per lane. LDS dest = wave-uniform base +
// lane*16 (hardware-defined); our staging layout is exactly linear.
// R14: aux=2 sets CPol NT (non-temporal, gfx940+ bit1) — the mask stream is
// single-use; NT marks it evict-first so it doesn't thrash L3/L2 (and stops
// evicting the 4 MB xt working set from L2). This is the ONLY change vs R6:
// clean A/B to decide L3-alloc choke vs genuine device read-rate ceiling.
__device__ __forceinline__ void gll16(const void* g, u32* l) {
    __builtin_amdgcn_global_load_lds((gu32*)g, (lu32*)l, 16, 0, /*aux=NT*/2);
}

// d_ws: xt = x transposed to (N, FIN), 4 MiB at offset 0.
__global__ __launch_bounds__(256)
void transpose_x_kernel(const float* __restrict__ x, float* __restrict__ xt) {
    int n = blockIdx.x * 256 + threadIdx.x;
    float v[FINC];
#pragma unroll
    for (int i = 0; i < FINC; ++i) v[i] = x[(size_t)i * NC + n];
    float4* dst = reinterpret_cast<float4*>(xt + ((size_t)n << 3));
    dst[0] = make_float4(v[0], v[1], v[2], v[3]);
    dst[1] = make_float4(v[4], v[5], v[6], v[7]);
}

// Structure identical to R6 (persistent blocks, gll double-buffer, one
// barrier per tile, lane-local mask rows in LDS). R6 counters: no spill
// (WRITE 8.2 MB), VALU 12%, 2.9 TB/s device-read — supply-capped: ~57 KB
// reads outstanding per CU continuously, implied queue latency ~5 us.
// R14 tests whether the ~3 TB/s read choke is the L3/L2 allocation path.
__global__ __launch_bounds__(BLOCK, 6)
void edge_conv_kernel(const float* __restrict__ xt,
                      const float* __restrict__ Wh, const float* __restrict__ Wv,
                      const float* __restrict__ bh, const float* __restrict__ bv,
                      const unsigned char* __restrict__ mh,
                      const unsigned char* __restrict__ mv,
                      const int* __restrict__ kh, const int* __restrict__ kv,
                      float* __restrict__ out)
{
    __shared__ __align__(16) u32 msh[2][TILE_WORDS];   // 2 x 13312 B

    const int tid  = threadIdx.x;
    const int lane = tid & 63;
    const int wave = tid >> 6;
    const int o    = lane >> 3;
    const int i    = lane & 7;

    const int  b     = blockIdx.x;
    const bool hor   = (b < GRIDH);
    const int  bb    = hor ? b : b - GRIDH;
    const int  cbase = hor ? 0 : L2C;

    const float*         W    = hor ? Wh : Wv;
    const float*         bias = hor ? bh : bv;
    const unsigned char* mask = hor ? mh : mv;
    const int*           ker  = hor ? kh : kv;

    // Mask-encoding probe (proven): int32/float32 0/1 masks have byte
    // offset%4==1 always zero; 1-byte bools are random. Grid-uniform.
    const unsigned char probe = mh[(size_t)(lane * 4 + 1)];
    const bool words = (__ballot(probe != 0) == 0ull);

    // Per-lane weight row + bias, loaded once (L2/L3-cached, reused 21x).
    float wreg[KC];
#pragma unroll
    for (int k = 0; k < KC; ++k) wreg[k] = W[lane * KC + k];
    const float biaso = bias[o];

    // Stage one tile into msh[buf] via global_load_lds (NT).
    // words: 832 uint4 = 13 chunks of 64; wave handles c = wave, wave+4,
    //        wave+8; wave 0 also c=12. LDS base uniform per instr; HW adds
    //        lane*16 -> linear, matching the flat tile layout.
    // bytes: 208 uint4 = chunks 0..2 (waves 0-2) + 16 uint4 (wave 3, lane<16).
    auto stage = [&](int buf, int t) {
        if (words) {
            const char* g = (const char*)mask + (size_t)t * TILE_WBYTES;
#pragma unroll
            for (int j = 0; j < 3; ++j) {
                const int c = wave + 4 * j;
                gll16(g + (size_t)(c * 64 + lane) * 16, &msh[buf][c * 256]);
            }
            if (wave == 0)
                gll16(g + (size_t)(12 * 64 + lane) * 16, &msh[buf][12 * 256]);
        } else {
            const char* g = (const char*)mask + (size_t)t * TILE_BBYTES;
            if (wave < 3)
                gll16(g + (size_t)(wave * 64 + lane) * 16, &msh[buf][wave * 256]);
            else if (lane < 16)
                gll16(g + (size_t)(3 * 64 + lane) * 16, &msh[buf][3 * 256]);
        }
    };

    int t = bb;
    stage(0, t);
    __syncthreads();                       // drains prologue glls (vmcnt 0)

    int buf = 0;
    for (; t < TPBR; t += GRIDH, buf ^= 1) {
        const int tn = t + GRIDH;
        if (tn < TPBR) stage(buf ^ 1, tn); // issue-early: lands under compute

        const int be  = t * EPB + wave;
        const int bes = __builtin_amdgcn_readfirstlane(be);  // force SMEM ker loads

        int cols[KC];
#pragma unroll
        for (int k = 0; k < KC; ++k) cols[k] = ker[(size_t)bes * KC + k];

        float acc0 = 0.0f, acc1 = 0.0f;
        if (words) {
            const u32* mrow = &msh[buf][wave * EWORDS + lane * KC];
#pragma unroll
            for (int k = 0; k < KC; ++k) {
                const float xv = xt[((size_t)cols[k] << 3) + i]; // 32 B seg / wave / k
                const float wm = mrow[k] ? wreg[k] : 0.0f;
                if (k & 1) acc1 = fmaf(wm, xv, acc1);
                else       acc0 = fmaf(wm, xv, acc0);
            }
        } else {
            const unsigned char* mrow = (const unsigned char*)&msh[buf][0]
                                        + wave * EWORDS + lane * KC;
#pragma unroll
            for (int k = 0; k < KC; ++k) {
                const float xv = xt[((size_t)cols[k] << 3) + i];
                const float wm = mrow[k] ? wreg[k] : 0.0f;
                if (k & 1) acc1 = fmaf(wm, xv, acc1);
                else       acc0 = fmaf(wm, xv, acc0);
            }
        }
        float acc = acc0 + acc1;
        acc += __shfl_xor(acc, 1);
        acc += __shfl_xor(acc, 2);
        acc += __shfl_xor(acc, 4);
        const float z = acc + biaso;

        __syncthreads();   // all waves done reading msh[buf]; glls for tn drained

        if (i == 0) {      // store after the barrier: keeps it out of the drain
            const float sig = 1.0f / (1.0f + __expf(-z));
            out[(size_t)o * NC + (cbase + be)] = (sig - 0.5f) * SCALE_F;
        }
    }
}

extern "C" void kernel_launch(void* const* d_in, const int* in_sizes, int n_in,
                              void* d_out, int out_size, void* d_ws, size_t ws_size,
                              hipStream_t stream) {
    const float*         x   = (const float*)d_in[0];
    const float*         Wh  = (const float*)d_in[1];
    const float*         Wv  = (const float*)d_in[2];
    const float*         bh  = (const float*)d_in[3];
    const float*         bv  = (const float*)d_in[4];
    const unsigned char* mh  = (const unsigned char*)d_in[5];
    const unsigned char* mv  = (const unsigned char*)d_in[6];
    const int*           kh  = (const int*)d_in[7];
    const int*           kv  = (const int*)d_in[8];
    float* out = (float*)d_out;
    float* xt  = (float*)d_ws;

    transpose_x_kernel<<<NC / 256, 256, 0, stream>>>(x, xt);
    edge_conv_kernel<<<GRID, BLOCK, 0, stream>>>(
        xt, Wh, Wv, bh, bv, mh, mv, kh, kv, out);
}